// Round 6
// baseline (2987.153 us; speedup 1.0000x reference)
//
#include <hip/hip_runtime.h>

// SentenceEncodingRNN2: 2-layer BiLSTM (T=256,B=128,D=300,H=256) + attention pooling.
// Round 15 == Round 14 resubmit (container infra failed; no counters returned).
// Dual-direction chain interleave. R11-R13 model: step wall =
//   visibility_latency (~2.3us, invariant) + serial_compute; nothing overlapped the
//   latency. Fix: each block owns BOTH directions for (h-slice s, batch-group g of
//   16): 64 blocks = 8s x 8g. Superstep: spin d0 -> MFMA d0 -> cells+stores d0 ->
//   spin d1 -> MFMA d1 -> cells+stores d1. Each chain's stores age through the
//   other chain's full phase before being polled (latency hidden under real work).
//   Ring = two packed-bf16 planes; producer stores at addr=tid (1KB contiguous per
//   wave), consumer polls 16KB contiguous coalesced dwords (R13 poll lesson).
//   Weights both dirs resident: 256 VGPR, statically indexed.
//   proj_gemm2 / attn_gemm / attn_final unchanged.

#define T_ 256
#define B_ 128
#define D_ 300
#define H_ 256
#define G4H 1024   // 4*H
#define H2 512     // 2*H
#define TC 64      // time-chunk length
#define LDK 40     // proj/attn LDS k-stride in bf16 (80 B rows)
#define LDA 264    // lstm A-tile LDS k-stride in bf16 (256+8)

typedef __attribute__((ext_vector_type(8))) short bf16x8;
typedef __attribute__((ext_vector_type(4))) short short4v;
typedef __attribute__((ext_vector_type(4))) float f32x4;

#define MFMA16(a, b, c) __builtin_amdgcn_mfma_f32_16x16x32_bf16(a, b, c, 0, 0, 0)
#define ATOM_ST(p, v) __hip_atomic_store((p), (v), __ATOMIC_RELAXED, __HIP_MEMORY_SCOPE_AGENT)
#define ATOM_LD(p) __hip_atomic_load((p), __ATOMIC_RELAXED, __HIP_MEMORY_SCOPE_AGENT)

// ---------------- helpers ----------------
__device__ __forceinline__ float sigf(float x) { return 1.f / (1.f + __expf(-x)); }
__device__ __forceinline__ float tanhfast(float x) { return 2.f / (1.f + __expf(-2.f * x)) - 1.f; }

__device__ __forceinline__ short hi_bf16(float x) {
  return (short)(__float_as_uint(x) >> 16);
}
__device__ __forceinline__ short lo_bf16(float x) {
  float lo = x - __uint_as_float(__float_as_uint(x) & 0xFFFF0000u);
  return (short)(__float_as_uint(lo) >> 16);
}

__device__ __forceinline__ void split_f4(const float4 v, short* hp, short* lp) {
  short4v h, l;
  h.x = hi_bf16(v.x); l.x = lo_bf16(v.x);
  h.y = hi_bf16(v.y); l.y = lo_bf16(v.y);
  h.z = hi_bf16(v.z); l.z = lo_bf16(v.z);
  h.w = hi_bf16(v.w); l.w = lo_bf16(v.w);
  *(short4v*)hp = h;
  *(short4v*)lp = l;
}

__device__ __forceinline__ void split8(const float4 v0, const float4 v1,
                                       bf16x8* hp, bf16x8* lp) {
  bf16x8 h, l;
  h[0] = hi_bf16(v0.x); l[0] = lo_bf16(v0.x);
  h[1] = hi_bf16(v0.y); l[1] = lo_bf16(v0.y);
  h[2] = hi_bf16(v0.z); l[2] = lo_bf16(v0.z);
  h[3] = hi_bf16(v0.w); l[3] = lo_bf16(v0.w);
  h[4] = hi_bf16(v1.x); l[4] = lo_bf16(v1.x);
  h[5] = hi_bf16(v1.y); l[5] = lo_bf16(v1.y);
  h[6] = hi_bf16(v1.z); l[6] = lo_bf16(v1.z);
  h[7] = hi_bf16(v1.w); l[7] = lo_bf16(v1.w);
  *hp = h; *lp = l;
}

// ---------------- dual-direction projection GEMM, split-bf16 MFMA ----------------
__global__ __launch_bounds__(256, 2) void proj_gemm2(
    const float* __restrict__ X,
    const float* __restrict__ W0, const float* __restrict__ W1,
    const float* __restrict__ b1f, const float* __restrict__ b2f,
    const float* __restrict__ b1r, const float* __restrict__ b2r,
    float* __restrict__ C0, float* __restrict__ C1,
    int N, int K, const int* __restrict__ lengths, int t0)
{
  __shared__ short Xh[128 * LDK], Xl[128 * LDK];
  __shared__ short Wh[128 * LDK], Wl[128 * LDK];
  const int rev = blockIdx.z;
  const float* __restrict__ W = rev ? W1 : W0;
  const float* __restrict__ bias1 = rev ? b1r : b1f;
  const float* __restrict__ bias2 = rev ? b2r : b2f;
  float* __restrict__ C = rev ? C1 : C0;

  const int tid = threadIdx.x;
  const int m0 = blockIdx.y * 128, n0 = blockIdx.x * 128;
  const int s_step = t0 + blockIdx.y;

  const int sr = tid >> 3;
  const int sc = (tid & 7) * 4;
  const float* px[4];
  const float* pw[4];
#pragma unroll
  for (int p = 0; p < 4; p++) {
    const int r = sr + p * 32;          // r == batch index within tile
    int ss = s_step;
    if (rev) {
      int lb = lengths[r]; if (lb < 1) lb = 1;
      ss = (s_step < lb) ? (lb - 1 - s_step) : s_step;
    }
    px[p] = X + (size_t)(ss * 128 + r) * K;
    pw[p] = W + (size_t)(n0 + r) * K;
  }

  const int lane = tid & 63, w = tid >> 6;
  const int mb = (w & 1) * 64, nb = (w >> 1) * 64;
  const int r16 = lane & 15, quad = lane >> 4;

  f32x4 acc[4][4];
#pragma unroll
  for (int i = 0; i < 4; i++)
#pragma unroll
    for (int j = 0; j < 4; j++) acc[i][j] = (f32x4){0.f, 0.f, 0.f, 0.f};

  for (int k0 = 0; k0 < K; k0 += 32) {
    const int gk = k0 + sc;
    const bool kin = (gk < K);          // K % 4 == 0 -> whole float4 in/out
#pragma unroll
    for (int p = 0; p < 4; p++) {
      float4 xv = {0.f, 0.f, 0.f, 0.f}, wv = {0.f, 0.f, 0.f, 0.f};
      if (kin) { xv = *(const float4*)(px[p] + gk); wv = *(const float4*)(pw[p] + gk); }
      const int ro = (sr + p * 32) * LDK + sc;
      split_f4(xv, &Xh[ro], &Xl[ro]);
      split_f4(wv, &Wh[ro], &Wl[ro]);
    }
    __syncthreads();

    bf16x8 ah[4], al[4], bh[4], bl[4];
#pragma unroll
    for (int mt = 0; mt < 4; mt++) {
      const int ro = (mb + mt * 16 + r16) * LDK + quad * 8;
      ah[mt] = *(const bf16x8*)&Xh[ro];
      al[mt] = *(const bf16x8*)&Xl[ro];
    }
#pragma unroll
    for (int nt = 0; nt < 4; nt++) {
      const int ro = (nb + nt * 16 + r16) * LDK + quad * 8;
      bh[nt] = *(const bf16x8*)&Wh[ro];
      bl[nt] = *(const bf16x8*)&Wl[ro];
    }
#pragma unroll
    for (int mt = 0; mt < 4; mt++)
#pragma unroll
      for (int nt = 0; nt < 4; nt++) {
        acc[mt][nt] = __builtin_amdgcn_mfma_f32_16x16x32_bf16(ah[mt], bh[nt], acc[mt][nt], 0, 0, 0);
        acc[mt][nt] = __builtin_amdgcn_mfma_f32_16x16x32_bf16(ah[mt], bl[nt], acc[mt][nt], 0, 0, 0);
        acc[mt][nt] = __builtin_amdgcn_mfma_f32_16x16x32_bf16(al[mt], bh[nt], acc[mt][nt], 0, 0, 0);
      }
    __syncthreads();
  }

  float bsum[4];
#pragma unroll
  for (int nt = 0; nt < 4; nt++) {
    const int col = n0 + nb + nt * 16 + r16;
    bsum[nt] = bias1[col] + bias2[col];
  }
#pragma unroll
  for (int mt = 0; mt < 4; mt++) {
    const int row = m0 + mb + mt * 16 + quad * 4;
#pragma unroll
    for (int nt = 0; nt < 4; nt++) {
      const int col = n0 + nb + nt * 16 + r16;
      float* Cp = C + (size_t)row * N + col;
#pragma unroll
      for (int reg = 0; reg < 4; reg++)
        Cp[(size_t)reg * N] = acc[mt][nt][reg] + bsum[nt];
    }
  }
}

// ---------------- attention score GEMM, split-bf16 MFMA, fused tanh*ctx ----------
__global__ __launch_bounds__(256, 2) void attn_gemm(
    const float* __restrict__ X, const float* __restrict__ W,
    const float* __restrict__ mlp_b, const float* __restrict__ ctx,
    float* __restrict__ scores, int M, int N, int K)
{
  __shared__ short Xh[128 * LDK], Xl[128 * LDK];
  __shared__ short Wh[128 * LDK], Wl[128 * LDK];
  const int tid = threadIdx.x;
  const int m0 = blockIdx.y * 128, n0 = blockIdx.x * 128;

  const int sr = tid >> 3;
  const int sc = (tid & 7) * 4;
  const float* px[4];
  const float* pw[4];
#pragma unroll
  for (int p = 0; p < 4; p++) {
    px[p] = X + (size_t)(m0 + sr + p * 32) * K;
    pw[p] = W + (size_t)(n0 + sr + p * 32) * K;
  }

  const int lane = tid & 63, w = tid >> 6;
  const int mb = (w & 1) * 64, nb = (w >> 1) * 64;
  const int r16 = lane & 15, quad = lane >> 4;

  f32x4 acc[4][4];
#pragma unroll
  for (int i = 0; i < 4; i++)
#pragma unroll
    for (int j = 0; j < 4; j++) acc[i][j] = (f32x4){0.f, 0.f, 0.f, 0.f};

  for (int k0 = 0; k0 < K; k0 += 32) {
    const int gk = k0 + sc;
#pragma unroll
    for (int p = 0; p < 4; p++) {
      float4 xv = *(const float4*)(px[p] + gk);
      float4 wv = *(const float4*)(pw[p] + gk);
      const int ro = (sr + p * 32) * LDK + sc;
      split_f4(xv, &Xh[ro], &Xl[ro]);
      split_f4(wv, &Wh[ro], &Wl[ro]);
    }
    __syncthreads();

    bf16x8 ah[4], al[4], bh[4], bl[4];
#pragma unroll
    for (int mt = 0; mt < 4; mt++) {
      const int ro = (mb + mt * 16 + r16) * LDK + quad * 8;
      ah[mt] = *(const bf16x8*)&Xh[ro];
      al[mt] = *(const bf16x8*)&Xl[ro];
    }
#pragma unroll
    for (int nt = 0; nt < 4; nt++) {
      const int ro = (nb + nt * 16 + r16) * LDK + quad * 8;
      bh[nt] = *(const bf16x8*)&Wh[ro];
      bl[nt] = *(const bf16x8*)&Wl[ro];
    }
#pragma unroll
    for (int mt = 0; mt < 4; mt++)
#pragma unroll
      for (int nt = 0; nt < 4; nt++) {
        acc[mt][nt] = __builtin_amdgcn_mfma_f32_16x16x32_bf16(ah[mt], bh[nt], acc[mt][nt], 0, 0, 0);
        acc[mt][nt] = __builtin_amdgcn_mfma_f32_16x16x32_bf16(ah[mt], bl[nt], acc[mt][nt], 0, 0, 0);
        acc[mt][nt] = __builtin_amdgcn_mfma_f32_16x16x32_bf16(al[mt], bh[nt], acc[mt][nt], 0, 0, 0);
      }
    __syncthreads();
  }

  float bb4[4], cc4[4];
#pragma unroll
  for (int nt = 0; nt < 4; nt++) {
    const int col = n0 + nb + nt * 16 + r16;
    bb4[nt] = mlp_b[col];
    cc4[nt] = ctx[col];
  }
#pragma unroll
  for (int mt = 0; mt < 4; mt++) {
#pragma unroll
    for (int reg = 0; reg < 4; reg++) {
      float ssum = 0.f;
#pragma unroll
      for (int nt = 0; nt < 4; nt++)
        ssum += tanhfast(acc[mt][nt][reg] + bb4[nt]) * cc4[nt];
      ssum += __shfl_xor(ssum, 1);
      ssum += __shfl_xor(ssum, 2);
      ssum += __shfl_xor(ssum, 4);
      ssum += __shfl_xor(ssum, 8);
      if (r16 == 0)
        atomicAdd(&scores[m0 + mb + mt * 16 + quad * 4 + reg], ssum);
    }
  }
}

// ---------------- LSTM recurrence -- R14: both dirs per block, 64 blocks ---------
// blk = s*8 + g: s = hdim slice (s*32..+31), g = batch group (g*16..+15), BOTH dirs.
// Partners (same g, varying s) share XCD (blk%8 = g).
// Ring (u32 view): [slot][d][g]{ plane0: [s'][b][hlp], plane1: ... } -- 4096 u32 per
// (slot,d,g); producer stores at +s*256+tid (contiguous); consumer reads the whole
// 16KB contiguous, coalesced. Packed u32 = (bf16 hi|lo pair for hl=2*hlp, 2*hlp+1).
// Superstep: [spin d0(t-1)] MFMA d0 | cells+stores d0 | [spin d1(t-1)] MFMA d1 |
// cells+stores d1. Each chain's stores age through the other chain's phase.
__global__ __launch_bounds__(256, 1) void lstm_rec(
    const float* __restrict__ xgF, const float* __restrict__ xgR,
    const float* __restrict__ whF, const float* __restrict__ whR,
    const int* __restrict__ lengths, float* __restrict__ hout,
    float* __restrict__ ring, float* __restrict__ bbuf, float* __restrict__ cbuf,
    int t0)
{
  __shared__ short Ah[2][16 * LDA];   // per chain: h(t-1) hi-plane, 16 batches
  __shared__ short Al[2][16 * LDA];   // lo-plane
  __shared__ float gbuf[16 * 128];    // gate pre-acts (shared by the two chains)

  const int tid = threadIdx.x;
  const int blk = blockIdx.x;
  const int s = blk >> 3;
  const int g = blk & 7;
  const int bbase = g * 16;
  unsigned* __restrict__ ring32 = (unsigned*)ring;

  const int lane = tid & 63;
  const int w = tid >> 6;              // wave index == gate index
  const int r16 = lane & 15, quad = lane >> 4;

  // cell mapping: thread owns cells (b = tid>>4, hl = 2*(tid&15) + {0,1}) per dir
  const int b = tid >> 4;              // 0..15
  const int hlp = tid & 15;            // 0..15
  const int hl0 = hlp * 2;
  const int bg = bbase + b;
  const int hdim0 = s * 32 + hl0;

  // ---- weight fragments, BOTH dirs (hi/lo bf16): 256 VGPR, statically indexed ----
  bf16x8 wbh[2][2][8], wbl[2][2][8];
#pragma unroll
  for (int dd = 0; dd < 2; dd++) {
    const float* whd = dd ? whR : whF;
#pragma unroll
    for (int nt = 0; nt < 2; nt++)
#pragma unroll
      for (int kt = 0; kt < 8; kt++) {
        const float* wr = whd + (size_t)(w * 256 + s * 32 + nt * 16 + r16) * 256
                              + kt * 32 + quad * 8;
        float4 v0 = *(const float4*)(wr);
        float4 v1 = *(const float4*)(wr + 4);
        split8(v0, v1, &wbh[dd][nt][kt], &wbl[dd][nt][kt]);
      }
  }

  // ---- lengths, initial x, c, A ----
  int lb = lengths[bg]; if (lb < 1) lb = 1;

  float2 xr[2][4];
#pragma unroll
  for (int dd = 0; dd < 2; dd++) {
    const float* xgd = dd ? xgR : xgF;
#pragma unroll
    for (int gate = 0; gate < 4; gate++)
      xr[dd][gate] = *(const float2*)(xgd + (size_t)bg * 1024 + gate * 256 + hdim0);
  }

  float cc[2][2];
  if (t0 == 0) {
    int* za = (int*)&Ah[0][0];
    int* zb = (int*)&Al[0][0];
    for (int i = tid; i < (2 * 16 * LDA) / 2; i += 256) { za[i] = 0; zb[i] = 0; }
    cc[0][0] = cc[0][1] = cc[1][0] = cc[1][1] = 0.f;
  } else {
    // stage A from bbuf (f32): thread covers (b2 = tid>>4, k0 = (tid&15)*16)
    const int b2 = tid >> 4, k0 = (tid & 15) * 16;
#pragma unroll
    for (int dd = 0; dd < 2; dd++) {
      const float* src = bbuf + ((size_t)dd * 128 + bbase + b2) * 256 + k0;
      float4 v0 = *(const float4*)(src);
      float4 v1 = *(const float4*)(src + 4);
      float4 v2 = *(const float4*)(src + 8);
      float4 v3 = *(const float4*)(src + 12);
      bf16x8 hv, lv;
      split8(v0, v1, &hv, &lv);
      *(bf16x8*)&Ah[dd][b2 * LDA + k0] = hv;
      *(bf16x8*)&Al[dd][b2 * LDA + k0] = lv;
      split8(v2, v3, &hv, &lv);
      *(bf16x8*)&Ah[dd][b2 * LDA + k0 + 8] = hv;
      *(bf16x8*)&Al[dd][b2 * LDA + k0 + 8] = lv;
      const float2 cv = *(const float2*)(cbuf + ((size_t)dd * 128 + bg) * 256 + hdim0);
      cc[dd][0] = cv.x; cc[dd][1] = cv.y;
    }
  }
  __syncthreads();

  // one chain phase: MFMA -> gbuf -> cells -> stores (+x prefetch)
  auto chain_phase = [&](int dd, int t) {
    const int slot = t - t0;
    const bool last = (t == t0 + TC - 1);

    // MFMA gate matvec: 48 MFMAs, 6 independent chains
    f32x4 aH0 = {0.f,0.f,0.f,0.f}, aM0 = {0.f,0.f,0.f,0.f}, aL0 = {0.f,0.f,0.f,0.f};
    f32x4 aH1 = {0.f,0.f,0.f,0.f}, aM1 = {0.f,0.f,0.f,0.f}, aL1 = {0.f,0.f,0.f,0.f};
#pragma unroll
    for (int kt = 0; kt < 8; kt++) {
      const int ro = r16 * LDA + kt * 32 + quad * 8;
      bf16x8 ahf = *(const bf16x8*)&Ah[dd][ro];
      bf16x8 alf = *(const bf16x8*)&Al[dd][ro];
      aH0 = MFMA16(ahf, wbh[dd][0][kt], aH0);
      aM0 = MFMA16(ahf, wbl[dd][0][kt], aM0);
      aL0 = MFMA16(alf, wbh[dd][0][kt], aL0);
      aH1 = MFMA16(ahf, wbh[dd][1][kt], aH1);
      aM1 = MFMA16(ahf, wbl[dd][1][kt], aM1);
      aL1 = MFMA16(alf, wbh[dd][1][kt], aL1);
    }
    // C layout: row m = quad*4+reg (batch 0..15), col n = r16
#pragma unroll
    for (int reg = 0; reg < 4; reg++) {
      gbuf[(quad * 4 + reg) * 128 + w * 32 + r16]      = aH0[reg] + aM0[reg] + aL0[reg];
      gbuf[(quad * 4 + reg) * 128 + w * 32 + 16 + r16] = aH1[reg] + aM1[reg] + aL1[reg];
    }
    __syncthreads();   // gbuf ready; A[dd] reads complete

    // cells (2 adjacent-hl cells per thread)
    const float2 g0 = *(const float2*)&gbuf[b * 128 +       hl0];
    const float2 g1 = *(const float2*)&gbuf[b * 128 +  32 + hl0];
    const float2 g2 = *(const float2*)&gbuf[b * 128 +  64 + hl0];
    const float2 g3 = *(const float2*)&gbuf[b * 128 +  96 + hl0];

    const float si0 = sigf(g0.x + xr[dd][0].x), si1 = sigf(g0.y + xr[dd][0].y);
    const float sf0 = sigf(g1.x + xr[dd][1].x), sf1 = sigf(g1.y + xr[dd][1].y);
    const float tg0 = tanhfast(g2.x + xr[dd][2].x), tg1 = tanhfast(g2.y + xr[dd][2].y);
    const float so0 = sigf(g3.x + xr[dd][3].x), so1 = sigf(g3.y + xr[dd][3].y);
    const float c0 = sf0 * cc[dd][0] + si0 * tg0;
    const float c1 = sf1 * cc[dd][1] + si1 * tg1;
    cc[dd][0] = c0; cc[dd][1] = c1;
    const float h0 = so0 * tanhfast(c0);
    const float h1 = so1 * tanhfast(c1);

    if (!last) {
      const unsigned ph = (unsigned)(unsigned short)hi_bf16(h0)
                        | ((unsigned)(unsigned short)hi_bf16(h1) << 16);
      const unsigned pl = (unsigned)(unsigned short)lo_bf16(h0)
                        | ((unsigned)(unsigned short)lo_bf16(h1) << 16);
      unsigned* rp = ring32 + (((size_t)slot * 2 + dd) * 8 + g) * 4096 + s * 256 + tid;
      ATOM_ST(rp, ph);
      ATOM_ST(rp + 2048, pl);
    } else {
      float2 hv; hv.x = h0; hv.y = h1;
      *(float2*)(bbuf + ((size_t)dd * 128 + bg) * 256 + hdim0) = hv;
    }
    const int tin = dd ? ((t < lb) ? (lb - 1 - t) : t) : t;
    float2 hv2; hv2.x = h0; hv2.y = h1;
    *(float2*)(hout + ((size_t)tin * 128 + bg) * 512 + dd * 256 + hdim0) = hv2;

    // prefetch x(t+1) for this chain (consumed next superstep)
    if (!last) {
      const float* xgd = dd ? xgR : xgF;
#pragma unroll
      for (int gate = 0; gate < 4; gate++)
        xr[dd][gate] = *(const float2*)(xgd +
            ((size_t)(slot + 1) * 128 + bg) * 1024 + gate * 256 + hdim0);
    }
  };

  // spin+stage chain dd's h(slotm1) into A[dd]; 16KB contiguous coalesced read
  auto spin_stage = [&](int dd, int slotm1) {
    const unsigned* su = ring32 + (((size_t)slotm1 * 2 + dd) * 8 + g) * 4096;
    unsigned uv[16];
    int it = 0;
    for (;;) {
      bool ok = true;
#pragma unroll
      for (int j = 0; j < 16; j++) {
        uv[j] = ATOM_LD(&su[j * 256 + tid]);
        ok &= (uv[j] != 0xFFFFFFFFu);
      }
      if (ok || ++it >= 20000) break;
    }
    // j<8: hi plane -> Ah; j>=8: lo plane -> Al. s' = j&7, row b = tid>>4, col hlp.
#pragma unroll
    for (int j = 0; j < 16; j++) {
      const int sp = j & 7;
      const int off = (tid >> 4) * LDA + sp * 32 + (tid & 15) * 2;
      if (j < 8) *(unsigned*)&Ah[dd][off] = uv[j];
      else       *(unsigned*)&Al[dd][off] = uv[j];
    }
  };

  const int tend = t0 + TC;
  for (int t = t0; t < tend; t++) {
    // ---- chain d0 ----
    if (t > t0) spin_stage(0, t - 1 - t0);
    __syncthreads();       // A0 staged; prev gbuf reads done before next write
    chain_phase(0, t);
    // ---- chain d1 ----
    if (t > t0) spin_stage(1, t - 1 - t0);
    __syncthreads();       // A1 staged; d0 gbuf reads done
    chain_phase(1, t);
  }

#pragma unroll
  for (int dd = 0; dd < 2; dd++) {
    float2 cv; cv.x = cc[dd][0]; cv.y = cc[dd][1];
    *(float2*)(cbuf + ((size_t)dd * 128 + bg) * 256 + hdim0) = cv;
  }
}

// ---------------- masked softmax over t + weighted sum ----------------
__global__ __launch_bounds__(256) void attn_final(
    const float* __restrict__ h2, const float* __restrict__ scores,
    const int* __restrict__ lengths, float* __restrict__ out)
{
  __shared__ float sl[256];
  __shared__ float red[256];
  const int b = blockIdx.x, tid = threadIdx.x;
  int lb = lengths[b]; if (lb < 1) lb = 1;
  const float sc = scores[(size_t)tid * 128 + b];
  const bool valid = (tid < lb);
  red[tid] = valid ? sc : -1e30f;
  __syncthreads();
  for (int off = 128; off > 0; off >>= 1) {
    if (tid < off) red[tid] = fmaxf(red[tid], red[tid + off]);
    __syncthreads();
  }
  const float mx = red[0];
  __syncthreads();
  const float p = valid ? __expf(sc - mx) : 0.f;
  red[tid] = p;
  __syncthreads();
  for (int off = 128; off > 0; off >>= 1) {
    if (tid < off) red[tid] += red[tid + off];
    __syncthreads();
  }
  const float inv = 1.f / red[0];
  __syncthreads();
  sl[tid] = p * inv;
  __syncthreads();

  float ax = 0.f, ay = 0.f;
  const int dd = tid * 2;
  for (int t = 0; t < 256; t++) {
    const float w = sl[t];
    if (w != 0.f) {
      const float* row = h2 + ((size_t)t * 128 + b) * 512 + dd;
      ax += w * row[0];
      ay += w * row[1];
    }
  }
  float2 r; r.x = ax; r.y = ay;
  *(float2*)(out + (size_t)b * 512 + dd) = r;
}

// ---------------- launch ----------------
extern "C" void kernel_launch(void* const* d_in, const int* in_sizes, int n_in,
                              void* d_out, int out_size, void* d_ws, size_t ws_size,
                              hipStream_t stream) {
  (void)in_sizes; (void)n_in; (void)out_size; (void)ws_size;
  const float* x        = (const float*)d_in[0];
  const int*   lengths  = (const int*)d_in[1];
  const float* w_ih_l0  = (const float*)d_in[2];
  const float* w_hh_l0  = (const float*)d_in[3];
  const float* b_ih_l0  = (const float*)d_in[4];
  const float* b_hh_l0  = (const float*)d_in[5];
  const float* w_ih_l0r = (const float*)d_in[6];
  const float* w_hh_l0r = (const float*)d_in[7];
  const float* b_ih_l0r = (const float*)d_in[8];
  const float* b_hh_l0r = (const float*)d_in[9];
  const float* w_ih_l1  = (const float*)d_in[10];
  const float* w_hh_l1  = (const float*)d_in[11];
  const float* b_ih_l1  = (const float*)d_in[12];
  const float* b_hh_l1  = (const float*)d_in[13];
  const float* w_ih_l1r = (const float*)d_in[14];
  const float* w_hh_l1r = (const float*)d_in[15];
  const float* b_ih_l1r = (const float*)d_in[16];
  const float* b_hh_l1r = (const float*)d_in[17];
  const float* mlp_w    = (const float*)d_in[18];
  const float* mlp_b    = (const float*)d_in[19];
  const float* ctx      = (const float*)d_in[20];
  float* out = (float*)d_out;

  // workspace layout (floats): ~219 MB
  float* ws = (float*)d_ws;
  const size_t XGC    = (size_t)TC * B_ * G4H;        // 8,388,608
  const size_t H_SZ   = (size_t)T_ * B_ * H2;         // 16,777,216
  const size_t RINGSZ = (size_t)TC * 2 * B_ * H_;     // 4,194,304 floats = 16 MB
  float* xgA    = ws;
  float* xgB    = xgA + XGC;
  float* h1     = xgB + XGC;
  float* h2     = h1 + H_SZ;
  float* ring   = h2 + H_SZ;
  float* bbuf   = ring + RINGSZ;                      // 65,536
  float* cbuf   = bbuf + 65536;                       // 65,536
  float* scores = cbuf + 65536;                       // 32,768

  (void)hipMemsetAsync(scores, 0, 32768 * 4, stream);

  dim3 blk(256);
  const dim3 pgrid(G4H / 128, TC, 2);   // (8, 64, 2 directions)

  // layer 0 (K=300), chunked over time
  for (int c = 0; c < T_ / TC; c++) {
    const int t0 = c * TC;
    proj_gemm2<<<pgrid, blk, 0, stream>>>(x, w_ih_l0, w_ih_l0r,
                                          b_ih_l0, b_hh_l0, b_ih_l0r, b_hh_l0r,
                                          xgA, xgB, G4H, D_, lengths, t0);
    (void)hipMemsetAsync(ring, 0xFF, RINGSZ * 4, stream);   // sentinel = 0xFFFFFFFF
    lstm_rec<<<64, blk, 0, stream>>>(xgA, xgB, w_hh_l0, w_hh_l0r, lengths, h1,
                                     ring, bbuf, cbuf, t0);
  }
  // layer 1 (K=512)
  for (int c = 0; c < T_ / TC; c++) {
    const int t0 = c * TC;
    proj_gemm2<<<pgrid, blk, 0, stream>>>(h1, w_ih_l1, w_ih_l1r,
                                          b_ih_l1, b_hh_l1, b_ih_l1r, b_hh_l1r,
                                          xgA, xgB, G4H, H2, lengths, t0);
    (void)hipMemsetAsync(ring, 0xFF, RINGSZ * 4, stream);
    lstm_rec<<<64, blk, 0, stream>>>(xgA, xgB, w_hh_l1, w_hh_l1r, lengths, h2,
                                     ring, bbuf, cbuf, t0);
  }
  // attention (M=32768, N=512, K=512)
  attn_gemm<<<dim3(H2 / 128, (T_ * B_) / 128), blk, 0, stream>>>(h2, mlp_w, mlp_b, ctx, scores, T_ * B_, H2, H2);
  attn_final<<<B_, blk, 0, stream>>>(h2, scores, lengths, out);
}